// Round 1
// baseline (620.261 us; speedup 1.0000x reference)
//
#include <hip/hip_runtime.h>
#include <hip/hip_bf16.h>

#define B_ 2
#define L_ 1024
#define D_ 1024
#define H_ 16
#define W_ 64
#define DH_ 64

#define TILE 64
#define KT 16

// C[m,n] = sum_k A[m,k] * B[n,k]
// A: M x K row-major, B: N x K row-major ("NT" gemm — both K-major)
// M, N multiples of 64; K multiple of 16. Block 256 threads, 64x64 tile,
// each thread computes a 4x4 micro-tile.
__global__ __launch_bounds__(256) void gemm_nt(const float* __restrict__ A,
                                               const float* __restrict__ B,
                                               float* __restrict__ C,
                                               int M, int N, int K) {
    __shared__ float As[KT][TILE + 1];  // +1 pad: kills 16-way bank conflict on store
    __shared__ float Bs[KT][TILE + 1];
    const int tid = threadIdx.x;
    const int m0 = blockIdx.x * TILE;
    const int n0 = blockIdx.y * TILE;
    const int tx = tid & 15;
    const int ty = tid >> 4;

    float acc[4][4];
#pragma unroll
    for (int i = 0; i < 4; ++i)
#pragma unroll
        for (int j = 0; j < 4; ++j) acc[i][j] = 0.f;

    for (int k0 = 0; k0 < K; k0 += KT) {
#pragma unroll
        for (int i = 0; i < 4; ++i) {
            int idx = tid + i * 256;
            int m = idx >> 4;   // 0..63
            int kk = idx & 15;  // 0..15
            As[kk][m] = A[(size_t)(m0 + m) * K + k0 + kk];
            Bs[kk][m] = B[(size_t)(n0 + m) * K + k0 + kk];
        }
        __syncthreads();
#pragma unroll
        for (int kk = 0; kk < KT; ++kk) {
            float a[4], b[4];
#pragma unroll
            for (int i = 0; i < 4; ++i) a[i] = As[kk][ty * 4 + i];
#pragma unroll
            for (int j = 0; j < 4; ++j) b[j] = Bs[kk][tx * 4 + j];
#pragma unroll
            for (int i = 0; i < 4; ++i)
#pragma unroll
                for (int j = 0; j < 4; ++j) acc[i][j] += a[i] * b[j];
        }
        __syncthreads();
    }

#pragma unroll
    for (int i = 0; i < 4; ++i) {
        int m = m0 + ty * 4 + i;
#pragma unroll
        for (int j = 0; j < 4; ++j) {
            C[(size_t)m * N + n0 + tx * 4 + j] = acc[i][j];
        }
    }
}

// One wave per query (b, l, h). Lane = window offset w for scores/softmax,
// lane = dh for the PV accumulation (attn broadcast via __shfl).
// q,k,v layout: (B, L, H, DH) fp32. lastk/lastv: (W-1, H, DH).
__global__ __launch_bounds__(256) void band_attn(const float* __restrict__ q,
                                                 const float* __restrict__ k,
                                                 const float* __restrict__ v,
                                                 const float* __restrict__ lastk,
                                                 const float* __restrict__ lastv,
                                                 float* __restrict__ out) {
    const int lane = threadIdx.x & 63;
    const int wave = threadIdx.x >> 6;
    const int l = blockIdx.x * 4 + wave;
    const int bh = blockIdx.y;
    const int b = bh >> 4;  // H_ == 16
    const int h = bh & 15;

    // ---- scores: lane = key offset w in [0, 64) ----
    const int pos = l + lane - (W_ - 1);  // original key position
    const float* krow;
    if (pos >= 0)
        krow = k + ((size_t)(b * L_ + pos) * H_ + h) * DH_;
    else
        krow = lastk + ((size_t)(l + lane) * H_ + h) * DH_;  // l+lane in [0, 62]

    const float* qrow = q + ((size_t)(b * L_ + l) * H_ + h) * DH_;

    float s = 0.f;
#pragma unroll 8
    for (int d = 0; d < DH_; ++d) s += qrow[d] * krow[d];
    s *= 0.125f;  // dh^-0.5 = 1/8

    // ---- wave softmax over 64 lanes ----
    float mx = s;
#pragma unroll
    for (int off = 32; off > 0; off >>= 1) mx = fmaxf(mx, __shfl_xor(mx, off, 64));
    float p = __expf(s - mx);
    float sum = p;
#pragma unroll
    for (int off = 32; off > 0; off >>= 1) sum += __shfl_xor(sum, off, 64);
    const float attn = p / sum;

    // ---- PV: lane = dh; iterate w, broadcasting attn_w ----
    float acc = 0.f;
    for (int w = 0; w < W_; ++w) {
        float aw = __shfl(attn, w, 64);
        int posw = l + w - (W_ - 1);  // wave-uniform branch
        const float* vr;
        if (posw >= 0)
            vr = v + ((size_t)(b * L_ + posw) * H_ + h) * DH_ + lane;
        else
            vr = lastv + ((size_t)(l + w) * H_ + h) * DH_ + lane;
        acc += aw * (*vr);
    }

    out[((size_t)(b * L_ + l) * H_ + h) * DH_ + lane] = acc;
}

extern "C" void kernel_launch(void* const* d_in, const int* in_sizes, int n_in,
                              void* d_out, int out_size, void* d_ws, size_t ws_size,
                              hipStream_t stream) {
    const float* x     = (const float*)d_in[0];
    const float* Wq    = (const float*)d_in[1];
    const float* Wk    = (const float*)d_in[2];
    const float* Wv    = (const float*)d_in[3];
    const float* Wo    = (const float*)d_in[4];
    const float* lastk = (const float*)d_in[5];
    const float* lastv = (const float*)d_in[6];
    float* out = (float*)d_out;

    const size_t nBLD = (size_t)B_ * L_ * D_;  // 2M elements, 8 MB each
    float* q  = (float*)d_ws;
    float* k  = q + nBLD;
    float* v  = k + nBLD;
    float* ao = v + nBLD;  // attention output (pre-Wo)

    const int M = B_ * L_;  // 2048
    dim3 gg(M / TILE, D_ / TILE);  // 32 x 16

    gemm_nt<<<gg, 256, 0, stream>>>(x, Wq, q, M, D_, D_);
    gemm_nt<<<gg, 256, 0, stream>>>(x, Wk, k, M, D_, D_);
    gemm_nt<<<gg, 256, 0, stream>>>(x, Wv, v, M, D_, D_);

    band_attn<<<dim3(L_ / 4, B_ * H_), 256, 0, stream>>>(q, k, v, lastk, lastv, ao);

    gemm_nt<<<gg, 256, 0, stream>>>(ao, Wo, out, M, D_, D_);
}

// Round 2
// 163.473 us; speedup vs baseline: 3.7943x; 3.7943x over previous
//
#include <hip/hip_runtime.h>
#include <hip/hip_bf16.h>
#include <stdint.h>

#define B_ 2
#define L_ 1024
#define D_ 1024
#define H_ 16
#define W_ 64
#define DH_ 64

typedef __attribute__((ext_vector_type(8))) __bf16 bf16x8;
typedef __attribute__((ext_vector_type(4))) float floatx4;

#define AS3(p) ((__attribute__((address_space(3))) void*)(p))
#define AS1(p) ((const __attribute__((address_space(1))) void*)(p))

static __device__ __forceinline__ ushort f2bf(float f) {
    union { float f; uint32_t u; } v{f};
    uint32_t r = v.u + 0x7fff + ((v.u >> 16) & 1);  // RNE
    return (ushort)(r >> 16);
}
static __device__ __forceinline__ float bflo(uint32_t u) { return __uint_as_float(u << 16); }
static __device__ __forceinline__ float bfhi(uint32_t u) { return __uint_as_float(u & 0xffff0000u); }

// ---------------- convert fp32 -> bf16 for x and the four weights ----------------
__global__ __launch_bounds__(256) void cvt_inputs(
    const float* __restrict__ x, const float* __restrict__ wq, const float* __restrict__ wk,
    const float* __restrict__ wv, const float* __restrict__ wo,
    ushort* __restrict__ xb, ushort* __restrict__ wqb, ushort* __restrict__ wkb,
    ushort* __restrict__ wvb, ushort* __restrict__ wob) {
    const size_t M1 = 1u << 20;
    size_t i4 = ((size_t)blockIdx.x * 256 + threadIdx.x) * 4;
    const float* s; ushort* d; size_t off;
    if (i4 < 2 * M1)      { s = x;  d = xb;  off = i4; }
    else if (i4 < 3 * M1) { s = wq; d = wqb; off = i4 - 2 * M1; }
    else if (i4 < 4 * M1) { s = wk; d = wkb; off = i4 - 3 * M1; }
    else if (i4 < 5 * M1) { s = wv; d = wvb; off = i4 - 4 * M1; }
    else                  { s = wo; d = wob; off = i4 - 5 * M1; }
    float4 f = *(const float4*)(s + off);
    ushort4 o;
    o.x = f2bf(f.x); o.y = f2bf(f.y); o.z = f2bf(f.z); o.w = f2bf(f.w);
    *(ushort4*)(d + off) = o;
}

// ---------------- fused QKV GEMM: q/k/v = x @ W^T, output head-major bf16 ----------------
#define BM 128
#define BN 128
#define BK 32

__global__ __launch_bounds__(256) void gemm_qkv(
    const ushort* __restrict__ xb,   // 2048 x 1024 bf16, K-major
    const ushort* __restrict__ wqb, const ushort* __restrict__ wkb, const ushort* __restrict__ wvb,
    ushort* __restrict__ q, ushort* __restrict__ k, ushort* __restrict__ v) {  // (B,H,L,DH) bf16
    __shared__ __align__(16) ushort As[BM * BK];
    __shared__ __align__(16) ushort Bs[BN * BK];
    const int tid = threadIdx.x;
    const int m0 = blockIdx.x * BM;
    const int nt = blockIdx.y;          // 0..23
    const int which = nt >> 3;
    const int n0 = (nt & 7) * BN;
    const ushort* wsel = which == 0 ? wqb : (which == 1 ? wkb : wvb);
    ushort* dsel = which == 0 ? q : (which == 1 ? k : v);

    const int lane = tid & 63;
    const int wv_ = tid >> 6;
    const int wm = (wv_ & 1) * 64;
    const int wn = (wv_ >> 1) * 64;
    const int lr = lane & 15;
    const int quad = lane >> 4;

    floatx4 acc[4][4];
#pragma unroll
    for (int i = 0; i < 4; ++i)
#pragma unroll
        for (int j = 0; j < 4; ++j) acc[i][j] = (floatx4){0.f, 0.f, 0.f, 0.f};

    const int srow = tid >> 2;        // 0..63
    const int sk8 = (tid & 3) * 8;
    const ushort* ga = xb + (size_t)(m0 + srow) * 1024 + sk8;
    const ushort* gb = wsel + (size_t)(n0 + srow) * 1024 + sk8;
    ushort* la = As + tid * 8;
    ushort* lb = Bs + tid * 8;

    for (int k0 = 0; k0 < 1024; k0 += BK) {
        __builtin_amdgcn_global_load_lds(AS1(ga),             AS3(la),            16, 0, 0);
        __builtin_amdgcn_global_load_lds(AS1(ga + 64 * 1024), AS3(la + 64 * BK),  16, 0, 0);
        __builtin_amdgcn_global_load_lds(AS1(gb),             AS3(lb),            16, 0, 0);
        __builtin_amdgcn_global_load_lds(AS1(gb + 64 * 1024), AS3(lb + 64 * BK),  16, 0, 0);
        ga += BK; gb += BK;
        __syncthreads();
        bf16x8 af[4], bfr[4];
#pragma unroll
        for (int i = 0; i < 4; ++i) af[i] = *(const bf16x8*)(As + (wm + i * 16 + lr) * BK + quad * 8);
#pragma unroll
        for (int j = 0; j < 4; ++j) bfr[j] = *(const bf16x8*)(Bs + (wn + j * 16 + lr) * BK + quad * 8);
#pragma unroll
        for (int i = 0; i < 4; ++i)
#pragma unroll
            for (int j = 0; j < 4; ++j)
                acc[i][j] = __builtin_amdgcn_mfma_f32_16x16x32_bf16(af[i], bfr[j], acc[i][j], 0, 0, 0);
        __syncthreads();
    }

#pragma unroll
    for (int i = 0; i < 4; ++i) {
        int rbase = m0 + wm + i * 16 + quad * 4;
#pragma unroll
        for (int j = 0; j < 4; ++j) {
            int c = n0 + wn + j * 16 + lr;
            int h = c >> 6, dh = c & 63;
#pragma unroll
            for (int r = 0; r < 4; ++r) {
                int m = rbase + r;
                int bb = m >> 10, l = m & 1023;
                dsel[(((size_t)bb * 16 + h) * 1024 + l) * 64 + dh] = f2bf(acc[i][j][r]);
            }
        }
    }
}

// ---------------- Wo GEMM: out = ao @ Wo^T, fp32 output ----------------
__global__ __launch_bounds__(256) void gemm_wo(
    const ushort* __restrict__ ab,   // 2048 x 1024 bf16
    const ushort* __restrict__ wob,
    float* __restrict__ out) {
    __shared__ __align__(16) ushort As[BM * BK];
    __shared__ __align__(16) ushort Bs[BN * BK];
    const int tid = threadIdx.x;
    const int m0 = blockIdx.x * BM;
    const int n0 = blockIdx.y * BN;
    const int lane = tid & 63;
    const int wv_ = tid >> 6;
    const int wm = (wv_ & 1) * 64;
    const int wn = (wv_ >> 1) * 64;
    const int lr = lane & 15;
    const int quad = lane >> 4;

    floatx4 acc[4][4];
#pragma unroll
    for (int i = 0; i < 4; ++i)
#pragma unroll
        for (int j = 0; j < 4; ++j) acc[i][j] = (floatx4){0.f, 0.f, 0.f, 0.f};

    const int srow = tid >> 2;
    const int sk8 = (tid & 3) * 8;
    const ushort* ga = ab + (size_t)(m0 + srow) * 1024 + sk8;
    const ushort* gb = wob + (size_t)(n0 + srow) * 1024 + sk8;
    ushort* la = As + tid * 8;
    ushort* lb = Bs + tid * 8;

    for (int k0 = 0; k0 < 1024; k0 += BK) {
        __builtin_amdgcn_global_load_lds(AS1(ga),             AS3(la),           16, 0, 0);
        __builtin_amdgcn_global_load_lds(AS1(ga + 64 * 1024), AS3(la + 64 * BK), 16, 0, 0);
        __builtin_amdgcn_global_load_lds(AS1(gb),             AS3(lb),           16, 0, 0);
        __builtin_amdgcn_global_load_lds(AS1(gb + 64 * 1024), AS3(lb + 64 * BK), 16, 0, 0);
        ga += BK; gb += BK;
        __syncthreads();
        bf16x8 af[4], bfr[4];
#pragma unroll
        for (int i = 0; i < 4; ++i) af[i] = *(const bf16x8*)(As + (wm + i * 16 + lr) * BK + quad * 8);
#pragma unroll
        for (int j = 0; j < 4; ++j) bfr[j] = *(const bf16x8*)(Bs + (wn + j * 16 + lr) * BK + quad * 8);
#pragma unroll
        for (int i = 0; i < 4; ++i)
#pragma unroll
            for (int j = 0; j < 4; ++j)
                acc[i][j] = __builtin_amdgcn_mfma_f32_16x16x32_bf16(af[i], bfr[j], acc[i][j], 0, 0, 0);
        __syncthreads();
    }

#pragma unroll
    for (int i = 0; i < 4; ++i) {
        int rbase = m0 + wm + i * 16 + quad * 4;
#pragma unroll
        for (int j = 0; j < 4; ++j) {
            int c = n0 + wn + j * 16 + lr;
#pragma unroll
            for (int r = 0; r < 4; ++r)
                out[(size_t)(rbase + r) * 1024 + c] = acc[i][j][r];
        }
    }
}

// ---------------- banded attention, LDS-staged ----------------
#define KSTR 66  // LDS row stride in ushorts (66*2=132B: row*33 banks -> conflict-free)

__global__ __launch_bounds__(256) void band_attn2(
    const ushort* __restrict__ q,    // (B,H,L,DH) bf16
    const ushort* __restrict__ k,
    const ushort* __restrict__ v,
    const float* __restrict__ lastk, // (63,H,DH) fp32
    const float* __restrict__ lastv,
    ushort* __restrict__ ao) {       // (B,L,D) bf16 row-major
    __shared__ ushort Ks[127 * KSTR + 8];
    __shared__ ushort Vs[127 * KSTR + 8];
    __shared__ ushort Qs[64 * KSTR];
    __shared__ float At[64 * 64];
    const int tid = threadIdx.x;
    const int lane = tid & 63;
    const int wid = tid >> 6;
    const int l0 = blockIdx.x * 64;
    const int bh = blockIdx.y;
    const int b = bh >> 4, h = bh & 15;
    const size_t hb = ((size_t)(b * 16 + h)) * 1024 * 64;  // head base (elements)

    // stage K/V window rows [l0-63 .. l0+63] -> rows 0..126
    for (int c = tid; c < 127 * 8; c += 256) {
        int r = c >> 3, c8 = (c & 7) * 8;
        int pos = l0 + r - 63;
        union { uint4 v4; uint32_t u[4]; } tk, tv;
        if (pos >= 0) {
            tk.v4 = *(const uint4*)(k + hb + (size_t)pos * 64 + c8);
            tv.v4 = *(const uint4*)(v + hb + (size_t)pos * 64 + c8);
        } else {  // only for l0==0: pos<0 => w = r in [0,62]
            const float* sk = lastk + ((size_t)r * 16 + h) * 64 + c8;
            const float* sv = lastv + ((size_t)r * 16 + h) * 64 + c8;
            float4 a0 = *(const float4*)sk, a1 = *(const float4*)(sk + 4);
            float4 b0 = *(const float4*)sv, b1 = *(const float4*)(sv + 4);
            tk.u[0] = f2bf(a0.x) | ((uint32_t)f2bf(a0.y) << 16);
            tk.u[1] = f2bf(a0.z) | ((uint32_t)f2bf(a0.w) << 16);
            tk.u[2] = f2bf(a1.x) | ((uint32_t)f2bf(a1.y) << 16);
            tk.u[3] = f2bf(a1.z) | ((uint32_t)f2bf(a1.w) << 16);
            tv.u[0] = f2bf(b0.x) | ((uint32_t)f2bf(b0.y) << 16);
            tv.u[1] = f2bf(b0.z) | ((uint32_t)f2bf(b0.w) << 16);
            tv.u[2] = f2bf(b1.x) | ((uint32_t)f2bf(b1.y) << 16);
            tv.u[3] = f2bf(b1.z) | ((uint32_t)f2bf(b1.w) << 16);
        }
#pragma unroll
        for (int t = 0; t < 4; ++t) {
            *(uint32_t*)(Ks + r * KSTR + c8 + 2 * t) = tk.u[t];
            *(uint32_t*)(Vs + r * KSTR + c8 + 2 * t) = tv.u[t];
        }
    }
    // stage Q rows l0..l0+63
    for (int c = tid; c < 64 * 8; c += 256) {
        int r = c >> 3, c8 = (c & 7) * 8;
        union { uint4 v4; uint32_t u[4]; } tq;
        tq.v4 = *(const uint4*)(q + hb + (size_t)(l0 + r) * 64 + c8);
#pragma unroll
        for (int t = 0; t < 4; ++t) *(uint32_t*)(Qs + r * KSTR + c8 + 2 * t) = tq.u[t];
    }
    __syncthreads();

    // scores + softmax: lane = window offset w; each wave owns 16 queries
    for (int qq = 0; qq < 16; ++qq) {
        int i = wid * 16 + qq;
        const ushort* krow = Ks + (i + lane) * KSTR;
        const ushort* qrow = Qs + i * KSTR;
        float s = 0.f;
#pragma unroll 8
        for (int d2 = 0; d2 < 32; ++d2) {
            uint32_t kk = *(const uint32_t*)(krow + 2 * d2);
            uint32_t qu = *(const uint32_t*)(qrow + 2 * d2);
            s = fmaf(bflo(kk), bflo(qu), s);
            s = fmaf(bfhi(kk), bfhi(qu), s);
        }
        s *= 0.125f;  // dh^-0.5
        float mx = s;
#pragma unroll
        for (int off = 32; off; off >>= 1) mx = fmaxf(mx, __shfl_xor(mx, off, 64));
        float p = __expf(s - mx);
        float sum = p;
#pragma unroll
        for (int off = 32; off; off >>= 1) sum += __shfl_xor(sum, off, 64);
        At[i * 64 + lane] = p / sum;
    }

    // PV: lane = dh
    for (int qq = 0; qq < 16; ++qq) {
        int i = wid * 16 + qq;
        const float* arow = At + i * 64;
        const ushort* vcol = Vs + i * KSTR + lane;
        float acc = 0.f;
#pragma unroll 8
        for (int w = 0; w < 64; ++w) {
            float aw = arow[w];
            float vv = bflo((uint32_t)vcol[(size_t)w * KSTR]);
            acc = fmaf(aw, vv, acc);
        }
        ao[((size_t)b * 1024 + l0 + i) * 1024 + h * 64 + lane] = f2bf(acc);
    }
}

extern "C" void kernel_launch(void* const* d_in, const int* in_sizes, int n_in,
                              void* d_out, int out_size, void* d_ws, size_t ws_size,
                              hipStream_t stream) {
    const float* x     = (const float*)d_in[0];
    const float* Wq    = (const float*)d_in[1];
    const float* Wk    = (const float*)d_in[2];
    const float* Wv    = (const float*)d_in[3];
    const float* Wo    = (const float*)d_in[4];
    const float* lastk = (const float*)d_in[5];
    const float* lastv = (const float*)d_in[6];
    float* out = (float*)d_out;

    const size_t M1 = 1u << 20;
    ushort* xb  = (ushort*)d_ws;          // 2M
    ushort* wqb = xb + 2 * M1;            // 1M
    ushort* wkb = wqb + M1;
    ushort* wvb = wkb + M1;
    ushort* wob = wvb + M1;
    ushort* qh  = wob + M1;               // 2M each, head-major
    ushort* kh  = qh + 2 * M1;
    ushort* vh  = kh + 2 * M1;
    ushort* ao  = vh + 2 * M1;            // 2M, row-major

    cvt_inputs<<<6144, 256, 0, stream>>>(x, Wq, Wk, Wv, Wo, xb, wqb, wkb, wvb, wob);
    gemm_qkv<<<dim3(16, 24), 256, 0, stream>>>(xb, wqb, wkb, wvb, qh, kh, vh);
    band_attn2<<<dim3(16, 32), 256, 0, stream>>>(qh, kh, vh, lastk, lastv, ao);
    gemm_wo<<<dim3(16, 8), 256, 0, stream>>>(ao, wob, out);
}

// Round 3
// 132.526 us; speedup vs baseline: 4.6803x; 1.2335x over previous
//
#include <hip/hip_runtime.h>
#include <hip/hip_bf16.h>
#include <stdint.h>

#define B_ 2
#define L_ 1024
#define D_ 1024
#define H_ 16
#define W_ 64
#define DH_ 64

typedef __attribute__((ext_vector_type(8))) __bf16 bf16x8;
typedef __attribute__((ext_vector_type(4))) float floatx4;

#define AS3(p) ((__attribute__((address_space(3))) void*)(p))
#define AS1(p) ((const __attribute__((address_space(1))) void*)(p))

static __device__ __forceinline__ ushort f2bf(float f) {
    union { float f; uint32_t u; } v{f};
    uint32_t r = v.u + 0x7fff + ((v.u >> 16) & 1);  // RNE
    return (ushort)(r >> 16);
}
static __device__ __forceinline__ uint32_t pack2(float a, float b) {
    return (uint32_t)f2bf(a) | ((uint32_t)f2bf(b) << 16);
}

// ---------------- convert fp32 -> bf16 for x and the four weights ----------------
__global__ __launch_bounds__(256) void cvt_inputs(
    const float* __restrict__ x, const float* __restrict__ wq, const float* __restrict__ wk,
    const float* __restrict__ wv, const float* __restrict__ wo,
    ushort* __restrict__ xb, ushort* __restrict__ wqb, ushort* __restrict__ wkb,
    ushort* __restrict__ wvb, ushort* __restrict__ wob) {
    const size_t M1 = 1u << 20;
    size_t i4 = ((size_t)blockIdx.x * 256 + threadIdx.x) * 4;
    const float* s; ushort* d; size_t off;
    if (i4 < 2 * M1)      { s = x;  d = xb;  off = i4; }
    else if (i4 < 3 * M1) { s = wq; d = wqb; off = i4 - 2 * M1; }
    else if (i4 < 4 * M1) { s = wk; d = wkb; off = i4 - 3 * M1; }
    else if (i4 < 5 * M1) { s = wv; d = wvb; off = i4 - 4 * M1; }
    else                  { s = wo; d = wob; off = i4 - 5 * M1; }
    float4 f = *(const float4*)(s + off);
    ushort4 o;
    o.x = f2bf(f.x); o.y = f2bf(f.y); o.z = f2bf(f.z); o.w = f2bf(f.w);
    *(ushort4*)(d + off) = o;
}

// ---------------- fused QKV GEMM: q/k/v = x @ W^T, output head-major bf16 ----------------
#define BM 128
#define BN 128
#define BK 32

__global__ __launch_bounds__(256) void gemm_qkv(
    const ushort* __restrict__ xb,   // 2048 x 1024 bf16, K-major
    const ushort* __restrict__ wqb, const ushort* __restrict__ wkb, const ushort* __restrict__ wvb,
    ushort* __restrict__ q, ushort* __restrict__ k, ushort* __restrict__ v) {  // (B,H,L,DH) bf16
    __shared__ __align__(16) ushort As[BM * BK];
    __shared__ __align__(16) ushort Bs[BN * BK];
    const int tid = threadIdx.x;
    const int m0 = blockIdx.x * BM;
    const int nt = blockIdx.y;          // 0..23
    const int which = nt >> 3;
    const int n0 = (nt & 7) * BN;
    const ushort* wsel = which == 0 ? wqb : (which == 1 ? wkb : wvb);
    ushort* dsel = which == 0 ? q : (which == 1 ? k : v);

    const int lane = tid & 63;
    const int wv_ = tid >> 6;
    const int wm = (wv_ & 1) * 64;
    const int wn = (wv_ >> 1) * 64;
    const int lr = lane & 15;
    const int quad = lane >> 4;

    floatx4 acc[4][4];
#pragma unroll
    for (int i = 0; i < 4; ++i)
#pragma unroll
        for (int j = 0; j < 4; ++j) acc[i][j] = (floatx4){0.f, 0.f, 0.f, 0.f};

    const int srow = tid >> 2;        // 0..63
    const int sk8 = (tid & 3) * 8;
    const ushort* ga = xb + (size_t)(m0 + srow) * 1024 + sk8;
    const ushort* gb = wsel + (size_t)(n0 + srow) * 1024 + sk8;
    ushort* la = As + tid * 8;
    ushort* lb = Bs + tid * 8;

    for (int k0 = 0; k0 < 1024; k0 += BK) {
        __builtin_amdgcn_global_load_lds(AS1(ga),             AS3(la),            16, 0, 0);
        __builtin_amdgcn_global_load_lds(AS1(ga + 64 * 1024), AS3(la + 64 * BK),  16, 0, 0);
        __builtin_amdgcn_global_load_lds(AS1(gb),             AS3(lb),            16, 0, 0);
        __builtin_amdgcn_global_load_lds(AS1(gb + 64 * 1024), AS3(lb + 64 * BK),  16, 0, 0);
        ga += BK; gb += BK;
        __syncthreads();
        bf16x8 af[4], bfr[4];
#pragma unroll
        for (int i = 0; i < 4; ++i) af[i] = *(const bf16x8*)(As + (wm + i * 16 + lr) * BK + quad * 8);
#pragma unroll
        for (int j = 0; j < 4; ++j) bfr[j] = *(const bf16x8*)(Bs + (wn + j * 16 + lr) * BK + quad * 8);
#pragma unroll
        for (int i = 0; i < 4; ++i)
#pragma unroll
            for (int j = 0; j < 4; ++j)
                acc[i][j] = __builtin_amdgcn_mfma_f32_16x16x32_bf16(af[i], bfr[j], acc[i][j], 0, 0, 0);
        __syncthreads();
    }

#pragma unroll
    for (int i = 0; i < 4; ++i) {
        int rbase = m0 + wm + i * 16 + quad * 4;
#pragma unroll
        for (int j = 0; j < 4; ++j) {
            int c = n0 + wn + j * 16 + lr;
            int h = c >> 6, dh = c & 63;
#pragma unroll
            for (int r = 0; r < 4; ++r) {
                int m = rbase + r;
                int bb = m >> 10, l = m & 1023;
                dsel[(((size_t)bb * 16 + h) * 1024 + l) * 64 + dh] = f2bf(acc[i][j][r]);
            }
        }
    }
}

// ---------------- Wo GEMM: out = ao @ Wo^T, fp32 output. 128x64 tile -> 256 blocks ----------------
__global__ __launch_bounds__(256) void gemm_wo(
    const ushort* __restrict__ ab,   // 2048 x 1024 bf16
    const ushort* __restrict__ wob,
    float* __restrict__ out) {
    __shared__ __align__(16) ushort As[128 * BK];
    __shared__ __align__(16) ushort Bs[64 * BK];
    const int tid = threadIdx.x;
    const int m0 = blockIdx.x * 128;
    const int n0 = blockIdx.y * 64;
    const int lane = tid & 63;
    const int wv_ = tid >> 6;
    const int wm = (wv_ & 1) * 64;
    const int wn = (wv_ >> 1) * 32;
    const int lr = lane & 15;
    const int quad = lane >> 4;

    floatx4 acc[4][2];
#pragma unroll
    for (int i = 0; i < 4; ++i)
#pragma unroll
        for (int j = 0; j < 2; ++j) acc[i][j] = (floatx4){0.f, 0.f, 0.f, 0.f};

    const int srow = tid >> 2;
    const int sk8 = (tid & 3) * 8;
    const ushort* ga = ab + (size_t)(m0 + srow) * 1024 + sk8;
    const ushort* gb = wob + (size_t)(n0 + srow) * 1024 + sk8;
    ushort* la = As + tid * 8;
    ushort* lb = Bs + tid * 8;

    for (int k0 = 0; k0 < 1024; k0 += BK) {
        __builtin_amdgcn_global_load_lds(AS1(ga),             AS3(la),           16, 0, 0);
        __builtin_amdgcn_global_load_lds(AS1(ga + 64 * 1024), AS3(la + 64 * BK), 16, 0, 0);
        __builtin_amdgcn_global_load_lds(AS1(gb),             AS3(lb),           16, 0, 0);
        ga += BK; gb += BK;
        __syncthreads();
        bf16x8 af[4], bfr[2];
#pragma unroll
        for (int i = 0; i < 4; ++i) af[i] = *(const bf16x8*)(As + (wm + i * 16 + lr) * BK + quad * 8);
#pragma unroll
        for (int j = 0; j < 2; ++j) bfr[j] = *(const bf16x8*)(Bs + (wn + j * 16 + lr) * BK + quad * 8);
#pragma unroll
        for (int i = 0; i < 4; ++i)
#pragma unroll
            for (int j = 0; j < 2; ++j)
                acc[i][j] = __builtin_amdgcn_mfma_f32_16x16x32_bf16(af[i], bfr[j], acc[i][j], 0, 0, 0);
        __syncthreads();
    }

#pragma unroll
    for (int i = 0; i < 4; ++i) {
        int rbase = m0 + wm + i * 16 + quad * 4;
#pragma unroll
        for (int j = 0; j < 2; ++j) {
            int c = n0 + wn + j * 16 + lr;
#pragma unroll
            for (int r = 0; r < 4; ++r)
                out[(size_t)(rbase + r) * 1024 + c] = acc[i][j][r];
        }
    }
}

// ---------------- banded attention via MFMA (flash-style, one 64-query tile/block) ----------------
#define STRQ 72    // LDS row stride (ushorts) for 64-wide rows: 144B, 16B-aligned, 2-way banks
#define STRV 136   // LDS row stride for 128-wide rows: 272B

__global__ __launch_bounds__(256) void band_attn3(
    const ushort* __restrict__ q,    // (B,H,L,DH) bf16
    const ushort* __restrict__ k,
    const ushort* __restrict__ v,
    const float* __restrict__ lastk, // (63,H,DH) fp32
    const float* __restrict__ lastv,
    ushort* __restrict__ ao) {       // (B,L,D) bf16 row-major
    __shared__ __align__(16) ushort Qs[64 * STRQ];
    __shared__ __align__(16) ushort Kw[128 * STRQ];
    __shared__ __align__(16) ushort Vt[64 * STRV];   // V^T: Vt[d][j]
    __shared__ __align__(16) ushort Ps[64 * STRV];   // P: row i, col j (A-layout for PV)
    const int tid = threadIdx.x;
    const int lane = tid & 63;
    const int wid = tid >> 6;
    const int l0 = blockIdx.x * 64;
    const int b = blockIdx.y >> 4, h = blockIdx.y & 15;
    const size_t hb = (size_t)(b * 16 + h) * 1024 * 64;

    // ---- stage Q (64x64) ----
    {
        int r = tid >> 2, c8 = (tid & 3) * 8;       // 256 threads cover 64x(4 chunks)... need 512 chunks
        // 64 rows x 8 chunks = 512 chunks; two per thread
#pragma unroll
        for (int it = 0; it < 2; ++it) {
            int c = tid + it * 256;
            int rr = c >> 3, cc = (c & 7) * 8;
            *(uint4*)(Qs + rr * STRQ + cc) = *(const uint4*)(q + hb + (size_t)(l0 + rr) * 64 + cc);
        }
        (void)r; (void)c8;
    }
    // ---- stage K window rows j=0..126 (pos = l0+j-63), row 127 zero ----
#pragma unroll
    for (int it = 0; it < 4; ++it) {
        int c = tid + it * 256;                      // 1024 chunks = 128 rows x 8
        int j = c >> 3, cc = (c & 7) * 8;
        int pos = l0 + j - 63;
        uint4 t = {0u, 0u, 0u, 0u};
        if (j < 127) {
            if (pos >= 0) {
                t = *(const uint4*)(k + hb + (size_t)pos * 64 + cc);
            } else {                                  // only l0==0, j in [0,62]
                const float* sk = lastk + ((size_t)j * 16 + h) * 64 + cc;
                float4 a0 = *(const float4*)sk, a1 = *(const float4*)(sk + 4);
                t.x = pack2(a0.x, a0.y); t.y = pack2(a0.z, a0.w);
                t.z = pack2(a1.x, a1.y); t.w = pack2(a1.z, a1.w);
            }
        }
        *(uint4*)(Kw + j * STRQ + cc) = t;
    }
    // ---- stage V window TRANSPOSED: Vt[d][j] ----
#pragma unroll
    for (int it = 0; it < 4; ++it) {
        int c = tid + it * 256;
        int j = c >> 3, d8 = (c & 7) * 8;
        int pos = l0 + j - 63;
        ushort tv[8];
        if (j >= 127) {
#pragma unroll
            for (int t = 0; t < 8; ++t) tv[t] = 0;
        } else if (pos >= 0) {
            union { uint4 u4; ushort us[8]; } tu;
            tu.u4 = *(const uint4*)(v + hb + (size_t)pos * 64 + d8);
#pragma unroll
            for (int t = 0; t < 8; ++t) tv[t] = tu.us[t];
        } else {
            const float* sv = lastv + ((size_t)j * 16 + h) * 64 + d8;
#pragma unroll
            for (int t = 0; t < 8; ++t) tv[t] = f2bf(sv[t]);
        }
#pragma unroll
        for (int t = 0; t < 8; ++t) Vt[(size_t)(d8 + t) * STRV + j] = tv[t];
    }
    __syncthreads();

    const int lr = lane & 15;
    const int quad = lane >> 4;

    // ---- scores: S = Q @ Kw^T  (m=16 rows/wave, n=128, k=64) ----
    floatx4 sa[8];
#pragma unroll
    for (int nt = 0; nt < 8; ++nt) sa[nt] = (floatx4){0.f, 0.f, 0.f, 0.f};
    bf16x8 aq[2];
#pragma unroll
    for (int ks = 0; ks < 2; ++ks)
        aq[ks] = *(const bf16x8*)(Qs + (wid * 16 + lr) * STRQ + ks * 32 + quad * 8);
#pragma unroll
    for (int ks = 0; ks < 2; ++ks)
#pragma unroll
        for (int nt = 0; nt < 8; ++nt) {
            bf16x8 bk = *(const bf16x8*)(Kw + (nt * 16 + lr) * STRQ + ks * 32 + quad * 8);
            sa[nt] = __builtin_amdgcn_mfma_f32_16x16x32_bf16(aq[ks], bk, sa[nt], 0, 0, 0);
        }

    // ---- in-register masked softmax; write P (bf16) to LDS in A-layout ----
#pragma unroll
    for (int rr = 0; rr < 4; ++rr) {
        int i_loc = wid * 16 + quad * 4 + rr;   // local query index (0..63)
        float sv[8];
        float mv = -1e30f;
#pragma unroll
        for (int nt = 0; nt < 8; ++nt) {
            int j = nt * 16 + lr;
            int w = j - i_loc;
            sv[nt] = (w >= 0 && w < 64) ? sa[nt][rr] * 0.125f : -1e30f;
            mv = fmaxf(mv, sv[nt]);
        }
#pragma unroll
        for (int off = 8; off; off >>= 1) mv = fmaxf(mv, __shfl_xor(mv, off, 16));
        float sum = 0.f;
#pragma unroll
        for (int nt = 0; nt < 8; ++nt) {
            sv[nt] = __expf(sv[nt] - mv);
            sum += sv[nt];
        }
#pragma unroll
        for (int off = 8; off; off >>= 1) sum += __shfl_xor(sum, off, 16);
        float inv = 1.f / sum;
#pragma unroll
        for (int nt = 0; nt < 8; ++nt)
            Ps[(size_t)i_loc * STRV + nt * 16 + lr] = f2bf(sv[nt] * inv);
    }
    // PV reads only rows wid*16..+15 of Ps — written by this same wave; no barrier needed.

    // ---- O = P @ Vw  (as NT: B = Vt[d][j]) ----
    floatx4 oa[4];
#pragma unroll
    for (int nt = 0; nt < 4; ++nt) oa[nt] = (floatx4){0.f, 0.f, 0.f, 0.f};
#pragma unroll
    for (int ks = 0; ks < 4; ++ks) {
        bf16x8 ap = *(const bf16x8*)(Ps + (wid * 16 + lr) * STRV + ks * 32 + quad * 8);
#pragma unroll
        for (int nt = 0; nt < 4; ++nt) {
            bf16x8 bv = *(const bf16x8*)(Vt + (nt * 16 + lr) * STRV + ks * 32 + quad * 8);
            oa[nt] = __builtin_amdgcn_mfma_f32_16x16x32_bf16(ap, bv, oa[nt], 0, 0, 0);
        }
    }

    // ---- store O: ao[b][l0+i][h*64+d] bf16 ----
#pragma unroll
    for (int nt = 0; nt < 4; ++nt) {
        int d = nt * 16 + lr;
#pragma unroll
        for (int rr = 0; rr < 4; ++rr) {
            int i_loc = wid * 16 + quad * 4 + rr;
            ao[((size_t)b * 1024 + l0 + i_loc) * 1024 + h * 64 + d] = f2bf(oa[nt][rr]);
        }
    }
}

extern "C" void kernel_launch(void* const* d_in, const int* in_sizes, int n_in,
                              void* d_out, int out_size, void* d_ws, size_t ws_size,
                              hipStream_t stream) {
    const float* x     = (const float*)d_in[0];
    const float* Wq    = (const float*)d_in[1];
    const float* Wk    = (const float*)d_in[2];
    const float* Wv    = (const float*)d_in[3];
    const float* Wo    = (const float*)d_in[4];
    const float* lastk = (const float*)d_in[5];
    const float* lastv = (const float*)d_in[6];
    float* out = (float*)d_out;

    const size_t M1 = 1u << 20;
    ushort* xb  = (ushort*)d_ws;          // 2M
    ushort* wqb = xb + 2 * M1;            // 1M
    ushort* wkb = wqb + M1;
    ushort* wvb = wkb + M1;
    ushort* wob = wvb + M1;
    ushort* qh  = wob + M1;               // 2M each, head-major (B,H,L,DH)
    ushort* kh  = qh + 2 * M1;
    ushort* vh  = kh + 2 * M1;
    ushort* ao  = vh + 2 * M1;            // 2M, row-major (B,L,D)

    cvt_inputs<<<6144, 256, 0, stream>>>(x, Wq, Wk, Wv, Wo, xb, wqb, wkb, wvb, wob);
    gemm_qkv<<<dim3(16, 24), 256, 0, stream>>>(xb, wqb, wkb, wvb, qh, kh, vh);
    band_attn3<<<dim3(16, 32), 256, 0, stream>>>(qh, kh, vh, lastk, lastv, ao);
    gemm_wo<<<dim3(16, 16), 256, 0, stream>>>(ao, wob, out);
}

// Round 4
// 128.431 us; speedup vs baseline: 4.8295x; 1.0319x over previous
//
#include <hip/hip_runtime.h>
#include <hip/hip_bf16.h>
#include <stdint.h>

#define B_ 2
#define L_ 1024
#define D_ 1024
#define H_ 16
#define W_ 64
#define DH_ 64

typedef __attribute__((ext_vector_type(8))) __bf16 bf16x8;
typedef __attribute__((ext_vector_type(4))) float floatx4;

#define AS3(p) ((__attribute__((address_space(3))) void*)(p))
#define AS1(p) ((const __attribute__((address_space(1))) void*)(p))

static __device__ __forceinline__ ushort f2bf(float f) {
    union { float f; uint32_t u; } v{f};
    uint32_t r = v.u + 0x7fff + ((v.u >> 16) & 1);  // RNE
    return (ushort)(r >> 16);
}
static __device__ __forceinline__ uint32_t pack2(float a, float b) {
    return (uint32_t)f2bf(a) | ((uint32_t)f2bf(b) << 16);
}

// ---------------- convert fp32 -> bf16 for x and the four weights ----------------
__global__ __launch_bounds__(256) void cvt_inputs(
    const float* __restrict__ x, const float* __restrict__ wq, const float* __restrict__ wk,
    const float* __restrict__ wv, const float* __restrict__ wo,
    ushort* __restrict__ xb, ushort* __restrict__ wqb, ushort* __restrict__ wkb,
    ushort* __restrict__ wvb, ushort* __restrict__ wob) {
    const size_t M1 = 1u << 20;
    size_t i4 = ((size_t)blockIdx.x * 256 + threadIdx.x) * 4;
    const float* s; ushort* d; size_t off;
    if (i4 < 2 * M1)      { s = x;  d = xb;  off = i4; }
    else if (i4 < 3 * M1) { s = wq; d = wqb; off = i4 - 2 * M1; }
    else if (i4 < 4 * M1) { s = wk; d = wkb; off = i4 - 3 * M1; }
    else if (i4 < 5 * M1) { s = wv; d = wvb; off = i4 - 4 * M1; }
    else                  { s = wo; d = wob; off = i4 - 5 * M1; }
    float4 f = *(const float4*)(s + off);
    ushort4 o;
    o.x = f2bf(f.x); o.y = f2bf(f.y); o.z = f2bf(f.z); o.w = f2bf(f.w);
    *(ushort4*)(d + off) = o;
}

// ---------------- fused QKV GEMM: q/k/v = x @ W^T, head-major bf16 out ----------------
// 128x128 tile, BK=64, XOR-swizzled LDS (slot s of row r holds k-chunk s^(r&7)).
#define BK 64

__global__ __launch_bounds__(256) void gemm_qkv(
    const ushort* __restrict__ xb,   // 2048 x 1024 bf16, K-major
    const ushort* __restrict__ wqb, const ushort* __restrict__ wkb, const ushort* __restrict__ wvb,
    ushort* __restrict__ q, ushort* __restrict__ k, ushort* __restrict__ v) {  // (B,H,L,DH) bf16
    __shared__ __align__(16) ushort As[128 * BK];
    __shared__ __align__(16) ushort Bs[128 * BK];
    const int tid = threadIdx.x;
    const int m0 = blockIdx.x * 128;
    const int nt = blockIdx.y;          // 0..23
    const int which = nt >> 3;
    const int n0 = (nt & 7) * 128;
    const ushort* wsel = which == 0 ? wqb : (which == 1 ? wkb : wvb);
    ushort* dsel = which == 0 ? q : (which == 1 ? k : v);

    const int lane = tid & 63;
    const int wv_ = tid >> 6;
    const int wm = (wv_ & 1) * 64;
    const int wn = (wv_ >> 1) * 64;
    const int lr = lane & 15;
    const int quad = lane >> 4;

    floatx4 acc[4][4];
#pragma unroll
    for (int i = 0; i < 4; ++i)
#pragma unroll
        for (int j = 0; j < 4; ++j) acc[i][j] = (floatx4){0.f, 0.f, 0.f, 0.f};

    // staging offsets: chunk c = tid + it*256 -> row r=c>>3, phys slot s=c&7,
    // global k-chunk g = s ^ (r&7). LDS dst = linear c*8 (lane-contiguous per wave).
    int offA[4], offB[4];
#pragma unroll
    for (int it = 0; it < 4; ++it) {
        int c = tid + it * 256;
        int r = c >> 3, s = c & 7, g = s ^ (r & 7);
        offA[it] = (m0 + r) * 1024 + g * 8;
        offB[it] = (n0 + r) * 1024 + g * 8;
    }

    for (int k0 = 0; k0 < 1024; k0 += BK) {
#pragma unroll
        for (int it = 0; it < 4; ++it)
            __builtin_amdgcn_global_load_lds(AS1(xb + offA[it] + k0), AS3(As + (it * 256 + tid) * 8), 16, 0, 0);
#pragma unroll
        for (int it = 0; it < 4; ++it)
            __builtin_amdgcn_global_load_lds(AS1(wsel + offB[it] + k0), AS3(Bs + (it * 256 + tid) * 8), 16, 0, 0);
        __syncthreads();
#pragma unroll
        for (int ks = 0; ks < 2; ++ks) {
            bf16x8 af[4], bfr[4];
#pragma unroll
            for (int i = 0; i < 4; ++i) {
                int r = wm + i * 16 + lr;
                af[i] = *(const bf16x8*)(As + r * BK + (((ks * 4 + quad) ^ (r & 7)) * 8));
            }
#pragma unroll
            for (int j = 0; j < 4; ++j) {
                int r = wn + j * 16 + lr;
                bfr[j] = *(const bf16x8*)(Bs + r * BK + (((ks * 4 + quad) ^ (r & 7)) * 8));
            }
#pragma unroll
            for (int i = 0; i < 4; ++i)
#pragma unroll
                for (int j = 0; j < 4; ++j)
                    acc[i][j] = __builtin_amdgcn_mfma_f32_16x16x32_bf16(af[i], bfr[j], acc[i][j], 0, 0, 0);
        }
        __syncthreads();
    }

#pragma unroll
    for (int i = 0; i < 4; ++i) {
        int rbase = m0 + wm + i * 16 + quad * 4;
#pragma unroll
        for (int j = 0; j < 4; ++j) {
            int c = n0 + wn + j * 16 + lr;
            int h = c >> 6, dh = c & 63;
#pragma unroll
            for (int r = 0; r < 4; ++r) {
                int m = rbase + r;
                int bb = m >> 10, l = m & 1023;
                dsel[(((size_t)bb * 16 + h) * 1024 + l) * 64 + dh] = f2bf(acc[i][j][r]);
            }
        }
    }
}

// ---------------- Wo GEMM: out = ao @ Wo^T, fp32 out. 128x64 tile, BK=64, swizzled ----------------
__global__ __launch_bounds__(256) void gemm_wo(
    const ushort* __restrict__ ab,   // 2048 x 1024 bf16
    const ushort* __restrict__ wob,
    float* __restrict__ out) {
    __shared__ __align__(16) ushort As[128 * BK];
    __shared__ __align__(16) ushort Bs[64 * BK];
    const int tid = threadIdx.x;
    const int m0 = blockIdx.x * 128;
    const int n0 = blockIdx.y * 64;
    const int lane = tid & 63;
    const int wv_ = tid >> 6;
    const int wm = (wv_ & 1) * 64;
    const int wn = (wv_ >> 1) * 32;
    const int lr = lane & 15;
    const int quad = lane >> 4;

    floatx4 acc[4][2];
#pragma unroll
    for (int i = 0; i < 4; ++i)
#pragma unroll
        for (int j = 0; j < 2; ++j) acc[i][j] = (floatx4){0.f, 0.f, 0.f, 0.f};

    int offA[4], offB[2];
#pragma unroll
    for (int it = 0; it < 4; ++it) {
        int c = tid + it * 256;
        int r = c >> 3, s = c & 7, g = s ^ (r & 7);
        offA[it] = (m0 + r) * 1024 + g * 8;
    }
#pragma unroll
    for (int it = 0; it < 2; ++it) {
        int c = tid + it * 256;
        int r = c >> 3, s = c & 7, g = s ^ (r & 7);
        offB[it] = (n0 + r) * 1024 + g * 8;
    }

    for (int k0 = 0; k0 < 1024; k0 += BK) {
#pragma unroll
        for (int it = 0; it < 4; ++it)
            __builtin_amdgcn_global_load_lds(AS1(ab + offA[it] + k0), AS3(As + (it * 256 + tid) * 8), 16, 0, 0);
#pragma unroll
        for (int it = 0; it < 2; ++it)
            __builtin_amdgcn_global_load_lds(AS1(wob + offB[it] + k0), AS3(Bs + (it * 256 + tid) * 8), 16, 0, 0);
        __syncthreads();
#pragma unroll
        for (int ks = 0; ks < 2; ++ks) {
            bf16x8 af[4], bfr[2];
#pragma unroll
            for (int i = 0; i < 4; ++i) {
                int r = wm + i * 16 + lr;
                af[i] = *(const bf16x8*)(As + r * BK + (((ks * 4 + quad) ^ (r & 7)) * 8));
            }
#pragma unroll
            for (int j = 0; j < 2; ++j) {
                int r = wn + j * 16 + lr;
                bfr[j] = *(const bf16x8*)(Bs + r * BK + (((ks * 4 + quad) ^ (r & 7)) * 8));
            }
#pragma unroll
            for (int i = 0; i < 4; ++i)
#pragma unroll
                for (int j = 0; j < 2; ++j)
                    acc[i][j] = __builtin_amdgcn_mfma_f32_16x16x32_bf16(af[i], bfr[j], acc[i][j], 0, 0, 0);
        }
        __syncthreads();
    }

#pragma unroll
    for (int i = 0; i < 4; ++i) {
        int rbase = m0 + wm + i * 16 + quad * 4;
#pragma unroll
        for (int j = 0; j < 2; ++j) {
            int c = n0 + wn + j * 16 + lr;
#pragma unroll
            for (int r = 0; r < 4; ++r)
                out[(size_t)(rbase + r) * 1024 + c] = acc[i][j][r];
        }
    }
}

// ---------------- banded attention via MFMA (flash-style, one 64-query tile/block) ----------------
#define STRQ 72    // LDS row stride (ushorts) for 64-wide rows
#define STRV 136   // LDS row stride for 128-wide rows

__global__ __launch_bounds__(256) void band_attn3(
    const ushort* __restrict__ q,    // (B,H,L,DH) bf16
    const ushort* __restrict__ k,
    const ushort* __restrict__ v,
    const float* __restrict__ lastk, // (63,H,DH) fp32
    const float* __restrict__ lastv,
    ushort* __restrict__ ao) {       // (B,L,D) bf16 row-major
    __shared__ __align__(16) ushort Qs[64 * STRQ];
    __shared__ __align__(16) ushort Kw[128 * STRQ];
    __shared__ __align__(16) ushort Vt[64 * STRV];   // V^T: Vt[d][j]
    __shared__ __align__(16) ushort Ps[64 * STRV];   // P: row i, col j (A-layout for PV)
    const int tid = threadIdx.x;
    const int lane = tid & 63;
    const int wid = tid >> 6;
    const int l0 = blockIdx.x * 64;
    const int b = blockIdx.y >> 4, h = blockIdx.y & 15;
    const size_t hb = (size_t)(b * 16 + h) * 1024 * 64;

    // ---- stage Q (64x64) ----
#pragma unroll
    for (int it = 0; it < 2; ++it) {
        int c = tid + it * 256;
        int rr = c >> 3, cc = (c & 7) * 8;
        *(uint4*)(Qs + rr * STRQ + cc) = *(const uint4*)(q + hb + (size_t)(l0 + rr) * 64 + cc);
    }
    // ---- stage K window rows j=0..126 (pos = l0+j-63), row 127 zero ----
#pragma unroll
    for (int it = 0; it < 4; ++it) {
        int c = tid + it * 256;
        int j = c >> 3, cc = (c & 7) * 8;
        int pos = l0 + j - 63;
        uint4 t = {0u, 0u, 0u, 0u};
        if (j < 127) {
            if (pos >= 0) {
                t = *(const uint4*)(k + hb + (size_t)pos * 64 + cc);
            } else {                                  // only l0==0, j in [0,62]
                const float* sk = lastk + ((size_t)j * 16 + h) * 64 + cc;
                float4 a0 = *(const float4*)sk, a1 = *(const float4*)(sk + 4);
                t.x = pack2(a0.x, a0.y); t.y = pack2(a0.z, a0.w);
                t.z = pack2(a1.x, a1.y); t.w = pack2(a1.z, a1.w);
            }
        }
        *(uint4*)(Kw + j * STRQ + cc) = t;
    }
    // ---- stage V window TRANSPOSED: Vt[d][j] ----
#pragma unroll
    for (int it = 0; it < 4; ++it) {
        int c = tid + it * 256;
        int j = c >> 3, d8 = (c & 7) * 8;
        int pos = l0 + j - 63;
        ushort tv[8];
        if (j >= 127) {
#pragma unroll
            for (int t = 0; t < 8; ++t) tv[t] = 0;
        } else if (pos >= 0) {
            union { uint4 u4; ushort us[8]; } tu;
            tu.u4 = *(const uint4*)(v + hb + (size_t)pos * 64 + d8);
#pragma unroll
            for (int t = 0; t < 8; ++t) tv[t] = tu.us[t];
        } else {
            const float* sv = lastv + ((size_t)j * 16 + h) * 64 + d8;
#pragma unroll
            for (int t = 0; t < 8; ++t) tv[t] = f2bf(sv[t]);
        }
#pragma unroll
        for (int t = 0; t < 8; ++t) Vt[(size_t)(d8 + t) * STRV + j] = tv[t];
    }
    __syncthreads();

    const int lr = lane & 15;
    const int quad = lane >> 4;

    // ---- scores: S = Q @ Kw^T  (m=16 rows/wave, n=128, k=64) ----
    floatx4 sa[8];
#pragma unroll
    for (int nt = 0; nt < 8; ++nt) sa[nt] = (floatx4){0.f, 0.f, 0.f, 0.f};
    bf16x8 aq[2];
#pragma unroll
    for (int ks = 0; ks < 2; ++ks)
        aq[ks] = *(const bf16x8*)(Qs + (wid * 16 + lr) * STRQ + ks * 32 + quad * 8);
#pragma unroll
    for (int ks = 0; ks < 2; ++ks)
#pragma unroll
        for (int nt = 0; nt < 8; ++nt) {
            bf16x8 bk = *(const bf16x8*)(Kw + (nt * 16 + lr) * STRQ + ks * 32 + quad * 8);
            sa[nt] = __builtin_amdgcn_mfma_f32_16x16x32_bf16(aq[ks], bk, sa[nt], 0, 0, 0);
        }

    // ---- in-register masked softmax; write P (bf16) to LDS in A-layout ----
#pragma unroll
    for (int rr = 0; rr < 4; ++rr) {
        int i_loc = wid * 16 + quad * 4 + rr;   // local query index (0..63)
        float sv[8];
        float mv = -1e30f;
#pragma unroll
        for (int nt = 0; nt < 8; ++nt) {
            int j = nt * 16 + lr;
            int w = j - i_loc;
            sv[nt] = (w >= 0 && w < 64) ? sa[nt][rr] * 0.125f : -1e30f;
            mv = fmaxf(mv, sv[nt]);
        }
#pragma unroll
        for (int off = 8; off; off >>= 1) mv = fmaxf(mv, __shfl_xor(mv, off, 16));
        float sum = 0.f;
#pragma unroll
        for (int nt = 0; nt < 8; ++nt) {
            sv[nt] = __expf(sv[nt] - mv);
            sum += sv[nt];
        }
#pragma unroll
        for (int off = 8; off; off >>= 1) sum += __shfl_xor(sum, off, 16);
        float inv = 1.f / sum;
#pragma unroll
        for (int nt = 0; nt < 8; ++nt)
            Ps[(size_t)i_loc * STRV + nt * 16 + lr] = f2bf(sv[nt] * inv);
    }
    // PV reads only rows wid*16..+15 of Ps — written by this same wave; no barrier needed.

    // ---- O = P @ Vw  (as NT: B = Vt[d][j]) ----
    floatx4 oa[4];
#pragma unroll
    for (int nt = 0; nt < 4; ++nt) oa[nt] = (floatx4){0.f, 0.f, 0.f, 0.f};
#pragma unroll
    for (int ks = 0; ks < 4; ++ks) {
        bf16x8 ap = *(const bf16x8*)(Ps + (wid * 16 + lr) * STRV + ks * 32 + quad * 8);
#pragma unroll
        for (int nt = 0; nt < 4; ++nt) {
            bf16x8 bv = *(const bf16x8*)(Vt + (nt * 16 + lr) * STRV + ks * 32 + quad * 8);
            oa[nt] = __builtin_amdgcn_mfma_f32_16x16x32_bf16(ap, bv, oa[nt], 0, 0, 0);
        }
    }

    // ---- store O: ao[b][l0+i][h*64+d] bf16 ----
#pragma unroll
    for (int nt = 0; nt < 4; ++nt) {
        int d = nt * 16 + lr;
#pragma unroll
        for (int rr = 0; rr < 4; ++rr) {
            int i_loc = wid * 16 + quad * 4 + rr;
            ao[((size_t)b * 1024 + l0 + i_loc) * 1024 + h * 64 + d] = f2bf(oa[nt][rr]);
        }
    }
}

extern "C" void kernel_launch(void* const* d_in, const int* in_sizes, int n_in,
                              void* d_out, int out_size, void* d_ws, size_t ws_size,
                              hipStream_t stream) {
    const float* x     = (const float*)d_in[0];
    const float* Wq    = (const float*)d_in[1];
    const float* Wk    = (const float*)d_in[2];
    const float* Wv    = (const float*)d_in[3];
    const float* Wo    = (const float*)d_in[4];
    const float* lastk = (const float*)d_in[5];
    const float* lastv = (const float*)d_in[6];
    float* out = (float*)d_out;

    const size_t M1 = 1u << 20;
    ushort* xb  = (ushort*)d_ws;          // 2M
    ushort* wqb = xb + 2 * M1;            // 1M
    ushort* wkb = wqb + M1;
    ushort* wvb = wkb + M1;
    ushort* wob = wvb + M1;
    ushort* qh  = wob + M1;               // 2M each, head-major (B,H,L,DH)
    ushort* kh  = qh + 2 * M1;
    ushort* vh  = kh + 2 * M1;
    ushort* ao  = vh + 2 * M1;            // 2M, row-major (B,L,D)

    cvt_inputs<<<6144, 256, 0, stream>>>(x, Wq, Wk, Wv, Wo, xb, wqb, wkb, wvb, wob);
    gemm_qkv<<<dim3(16, 24), 256, 0, stream>>>(xb, wqb, wkb, wvb, qh, kh, vh);
    band_attn3<<<dim3(16, 32), 256, 0, stream>>>(qh, kh, vh, lastk, lastv, ao);
    gemm_wo<<<dim3(16, 16), 256, 0, stream>>>(ao, wob, out);
}